// Round 1
// baseline (1896.690 us; speedup 1.0000x reference)
//
#include <hip/hip_runtime.h>
#include <hip/hip_bf16.h>
#include <math.h>

typedef __bf16 bf16_t;
typedef __bf16 bf16x8 __attribute__((ext_vector_type(8)));
typedef __bf16 bf16x4 __attribute__((ext_vector_type(4)));
typedef __bf16 bf16x2 __attribute__((ext_vector_type(2)));
typedef float  f32x4  __attribute__((ext_vector_type(4)));

#define HIDN 3072
#define LQ   2048
#define NH   24
#define HD   128
#define N1   21504   // 3*HID + MLP
#define N2   15360   // HID + MLP
#define KIP  4096

__device__ __forceinline__ f32x4 mfma16(bf16x8 a, bf16x8 b, f32x4 c) {
    return __builtin_amdgcn_mfma_f32_16x16x32_bf16(a, b, c, 0, 0, 0);
}

__device__ __forceinline__ float wave_sum64(float v) {
#pragma unroll
    for (int off = 1; off < 64; off <<= 1) v += __shfl_xor(v, off);
    return v;
}

// ---------------- convert image_proj fp32 -> bf16 ----------------
__global__ void k_convert(const float* __restrict__ in, bf16_t* __restrict__ out, int n4) {
    int i = blockIdx.x * blockDim.x + threadIdx.x;
    if (i < n4) {
        float4 f = ((const float4*)in)[i];
        bf16x4 h = {(bf16_t)f.x, (bf16_t)f.y, (bf16_t)f.z, (bf16_t)f.w};
        *(bf16x4*)(out + (size_t)i * 4) = h;
    }
}

// ---------------- mod = silu(vec) @ W^T + b  (9216 rows) ----------------
__global__ __launch_bounds__(256) void k_mod_gemv(const float* __restrict__ vec,
                                                  const float* __restrict__ W,
                                                  const float* __restrict__ b,
                                                  float* __restrict__ mod) {
    int row  = blockIdx.x * 4 + (threadIdx.x >> 6);
    int lane = threadIdx.x & 63;
    const float4* W4 = (const float4*)(W + (size_t)row * HIDN);
    const float4* V4 = (const float4*)vec;
    float s = 0.f;
#pragma unroll
    for (int i = 0; i < 12; i++) {
        float4 w = W4[lane + i * 64];
        float4 v = V4[lane + i * 64];
        s += w.x * (v.x / (1.f + __expf(-v.x)));
        s += w.y * (v.y / (1.f + __expf(-v.y)));
        s += w.z * (v.z / (1.f + __expf(-v.z)));
        s += w.w * (v.w / (1.f + __expf(-v.w)));
    }
    s = wave_sum64(s);
    if (lane == 0) mod[row] = s + b[row];
}

// ---------------- x_mod = (1+scale)*LN(x) + shift, bf16 out ----------------
__global__ __launch_bounds__(256) void k_ln_mod(const float* __restrict__ x,
                                                const float* __restrict__ mod,
                                                bf16_t* __restrict__ x_mod) {
    int row = blockIdx.x, tid = threadIdx.x;
    const float* xr = x + (size_t)row * HIDN;
    float v[12];
    float s = 0.f, ss = 0.f;
#pragma unroll
    for (int p = 0; p < 12; p++) {
        v[p] = xr[tid + p * 256];
        s += v[p]; ss += v[p] * v[p];
    }
    s = wave_sum64(s); ss = wave_sum64(ss);
    __shared__ float red[8];
    int wave = tid >> 6, lane = tid & 63;
    if (lane == 0) { red[wave] = s; red[4 + wave] = ss; }
    __syncthreads();
    float S  = red[0] + red[1] + red[2] + red[3];
    float SS = red[4] + red[5] + red[6] + red[7];
    float mean = S * (1.f / HIDN);
    float var  = SS * (1.f / HIDN) - mean * mean;
    float rstd = rsqrtf(var + 1e-6f);
#pragma unroll
    for (int p = 0; p < 12; p++) {
        int j = tid + p * 256;
        float xm = (v[p] - mean) * rstd;
        float y  = (1.f + mod[HIDN + j]) * xm + mod[j];
        x_mod[(size_t)row * HIDN + j] = (bf16_t)y;
    }
}

// ---------------- shared 128x128 GEMM core: C = A(bf16,MxK) @ W^T(fp32,NxK) ----------------
__device__ __forceinline__ void gemm_core(const bf16_t* __restrict__ A,
                                          const float* __restrict__ W,
                                          int K, int m0, int n0,
                                          bf16_t* a_sh, bf16_t* b_sh,
                                          f32x4 acc[4][4]) {
    const int tid = threadIdx.x;
    const int wave = tid >> 6, lane = tid & 63;
    const int qd = lane >> 4, tr = lane & 15;
    const int wm = (wave >> 1) * 64, wn = (wave & 1) * 64;
    for (int k0 = 0; k0 < K; k0 += 32) {
        __syncthreads();
#pragma unroll
        for (int i = 0; i < 2; i++) {
            int flat = tid + i * 256;
            int r = flat >> 2, s = flat & 3;
            *(bf16x8*)(a_sh + r * 40 + s * 8) =
                *(const bf16x8*)(A + (size_t)(m0 + r) * K + k0 + s * 8);
        }
#pragma unroll
        for (int i = 0; i < 4; i++) {
            int flat = tid + i * 256;
            int r = flat >> 3, s = flat & 7;
            float4 f = *(const float4*)(W + (size_t)(n0 + r) * K + k0 + s * 4);
            bf16x4 h = {(bf16_t)f.x, (bf16_t)f.y, (bf16_t)f.z, (bf16_t)f.w};
            *(bf16x4*)(b_sh + r * 40 + s * 4) = h;
        }
        __syncthreads();
        bf16x8 af[4], bfr[4];
#pragma unroll
        for (int t = 0; t < 4; t++)
            af[t] = *(const bf16x8*)(a_sh + (wm + t * 16 + tr) * 40 + qd * 8);
#pragma unroll
        for (int t = 0; t < 4; t++)
            bfr[t] = *(const bf16x8*)(b_sh + (wn + t * 16 + tr) * 40 + qd * 8);
#pragma unroll
        for (int mt = 0; mt < 4; mt++)
#pragma unroll
            for (int nt = 0; nt < 4; nt++)
                acc[mt][nt] = mfma16(af[mt], bfr[nt], acc[mt][nt]);
    }
}

// ---------------- linear1: h = x_mod @ W1^T + b1; qkv -> hq, gelu(mlp) -> fused ----------------
__global__ __launch_bounds__(256) void k_gemm_l1(const bf16_t* __restrict__ A,
                                                 const float* __restrict__ W,
                                                 const float* __restrict__ bias,
                                                 bf16_t* __restrict__ hq,
                                                 bf16_t* __restrict__ fused) {
    __shared__ bf16_t a_sh[128 * 40];
    __shared__ bf16_t b_sh[128 * 40];
    f32x4 acc[4][4];
    const f32x4 z = {0.f, 0.f, 0.f, 0.f};
#pragma unroll
    for (int mt = 0; mt < 4; mt++)
#pragma unroll
        for (int nt = 0; nt < 4; nt++) acc[mt][nt] = z;
    int m0 = blockIdx.x * 128, n0 = blockIdx.y * 128;
    gemm_core(A, W, HIDN, m0, n0, a_sh, b_sh, acc);
    const int tid = threadIdx.x, wave = tid >> 6, lane = tid & 63;
    const int qd = lane >> 4, tr = lane & 15;
    const int wm = (wave >> 1) * 64, wn = (wave & 1) * 64;
#pragma unroll
    for (int mt = 0; mt < 4; mt++)
#pragma unroll
        for (int nt = 0; nt < 4; nt++) {
            int col = n0 + wn + nt * 16 + tr;
            float bb = bias[col];
            f32x4 v = acc[mt][nt];
#pragma unroll
            for (int r = 0; r < 4; r++) {
                int row = m0 + wm + mt * 16 + qd * 4 + r;
                float val = v[r] + bb;
                if (col < 9216) {
                    hq[(size_t)row * 9216 + col] = (bf16_t)val;
                } else {
                    float g = 0.5f * val *
                        (1.f + tanhf(0.7978845608028654f * (val + 0.044715f * val * val * val)));
                    fused[(size_t)row * N2 + HIDN + (col - 9216)] = (bf16_t)g;
                }
            }
        }
}

// ---------------- linear2: out = x + gate * (fused @ W2^T + b2) ----------------
__global__ __launch_bounds__(256) void k_gemm_l2(const bf16_t* __restrict__ A,
                                                 const float* __restrict__ W,
                                                 const float* __restrict__ bias,
                                                 const float* __restrict__ x,
                                                 const float* __restrict__ gate,
                                                 float* __restrict__ out) {
    __shared__ bf16_t a_sh[128 * 40];
    __shared__ bf16_t b_sh[128 * 40];
    f32x4 acc[4][4];
    const f32x4 z = {0.f, 0.f, 0.f, 0.f};
#pragma unroll
    for (int mt = 0; mt < 4; mt++)
#pragma unroll
        for (int nt = 0; nt < 4; nt++) acc[mt][nt] = z;
    int m0 = blockIdx.x * 128, n0 = blockIdx.y * 128;
    gemm_core(A, W, N2, m0, n0, a_sh, b_sh, acc);
    const int tid = threadIdx.x, wave = tid >> 6, lane = tid & 63;
    const int qd = lane >> 4, tr = lane & 15;
    const int wm = (wave >> 1) * 64, wn = (wave & 1) * 64;
#pragma unroll
    for (int mt = 0; mt < 4; mt++)
#pragma unroll
        for (int nt = 0; nt < 4; nt++) {
            int col = n0 + wn + nt * 16 + tr;
            float bb = bias[col];
            float g  = gate[col];
#pragma unroll
            for (int r = 0; r < 4; r++) {
                int row = m0 + wm + mt * 16 + qd * 4 + r;
                size_t idx = (size_t)row * HIDN + col;
                out[idx] = x[idx] + g * (acc[mt][nt][r] + bb);
            }
        }
}

// ---------------- ip_k / ip_v: (64x4096)@(3072x4096)^T -> (H,64,128) bf16 ----------------
__global__ __launch_bounds__(256) void k_gemm_ip(const bf16_t* __restrict__ A,
                                                 const float* __restrict__ Wk,
                                                 const float* __restrict__ Wv,
                                                 bf16_t* __restrict__ outk,
                                                 bf16_t* __restrict__ outv) {
    __shared__ bf16_t a_sh[64 * 40];
    __shared__ bf16_t b_sh[64 * 40];
    const float* W = (blockIdx.y == 0) ? Wk : Wv;
    bf16_t* out    = (blockIdx.y == 0) ? outk : outv;
    int n0 = blockIdx.x * 64;
    const int tid = threadIdx.x, wave = tid >> 6, lane = tid & 63;
    const int qd = lane >> 4, tr = lane & 15;
    f32x4 acc[4];
    const f32x4 z = {0.f, 0.f, 0.f, 0.f};
#pragma unroll
    for (int mt = 0; mt < 4; mt++) acc[mt] = z;
    for (int k0 = 0; k0 < KIP; k0 += 32) {
        __syncthreads();
        {
            int r = tid >> 2, s = tid & 3;
            *(bf16x8*)(a_sh + r * 40 + s * 8) =
                *(const bf16x8*)(A + (size_t)r * KIP + k0 + s * 8);
        }
#pragma unroll
        for (int i = 0; i < 2; i++) {
            int flat = tid + i * 256;
            int r = flat >> 3, s = flat & 7;
            float4 f = *(const float4*)(W + (size_t)(n0 + r) * KIP + k0 + s * 4);
            bf16x4 h = {(bf16_t)f.x, (bf16_t)f.y, (bf16_t)f.z, (bf16_t)f.w};
            *(bf16x4*)(b_sh + r * 40 + s * 4) = h;
        }
        __syncthreads();
        bf16x8 bfrag = *(const bf16x8*)(b_sh + (wave * 16 + tr) * 40 + qd * 8);
#pragma unroll
        for (int mt = 0; mt < 4; mt++) {
            bf16x8 afrag = *(const bf16x8*)(a_sh + (mt * 16 + tr) * 40 + qd * 8);
            acc[mt] = mfma16(afrag, bfrag, acc[mt]);
        }
    }
    int col = n0 + wave * 16 + tr;
    int h = col >> 7, d = col & 127;
#pragma unroll
    for (int mt = 0; mt < 4; mt++)
#pragma unroll
        for (int r = 0; r < 4; r++) {
            int row = mt * 16 + qd * 4 + r;
            out[((size_t)h * 64 + row) * HD + d] = (bf16_t)acc[mt][r];
        }
}

// ---------------- qkv post: rmsnorm + rope, repack to (H,L,D) bf16 ----------------
__global__ __launch_bounds__(256) void k_qkv_post(const bf16_t* __restrict__ hq,
                                                  const float* __restrict__ pe,
                                                  const float* __restrict__ qs,
                                                  const float* __restrict__ ksc,
                                                  bf16_t* __restrict__ q_rope,
                                                  bf16_t* __restrict__ k_rope,
                                                  bf16_t* __restrict__ q_plain,
                                                  bf16_t* __restrict__ v_buf) {
    int wid  = blockIdx.x * 4 + (threadIdx.x >> 6);
    int lane = threadIdx.x & 63;
    int l = wid / NH, h = wid % NH;
    const bf16_t* base = hq + (size_t)l * 9216 + h * HD;
    int d0 = lane * 2;
    float q0 = (float)base[d0],        q1 = (float)base[d0 + 1];
    float k0 = (float)base[3072 + d0], k1 = (float)base[3072 + d0 + 1];
    bf16_t v0 = base[6144 + d0],       v1 = base[6144 + d0 + 1];
    float ssq = wave_sum64(q0 * q0 + q1 * q1);
    float ssk = wave_sum64(k0 * k0 + k1 * k1);
    float rq = rsqrtf(ssq * (1.f / HD) + 1e-6f);
    float rk = rsqrtf(ssk * (1.f / HD) + 1e-6f);
    float qn0 = q0 * rq * qs[d0], qn1 = q1 * rq * qs[d0 + 1];
    float kn0 = k0 * rk * ksc[d0], kn1 = k1 * rk * ksc[d0 + 1];
    const float* pp = pe + ((size_t)l * 64 + lane) * 4;
    float c00 = pp[0], c01 = pp[1], c10 = pp[2], c11 = pp[3];
    size_t oidx = ((size_t)h * LQ + l) * HD + d0;
    q_rope[oidx]     = (bf16_t)(c00 * qn0 + c01 * qn1);
    q_rope[oidx + 1] = (bf16_t)(c10 * qn0 + c11 * qn1);
    k_rope[oidx]     = (bf16_t)(c00 * kn0 + c01 * kn1);
    k_rope[oidx + 1] = (bf16_t)(c10 * kn0 + c11 * kn1);
    q_plain[oidx]     = (bf16_t)qn0;
    q_plain[oidx + 1] = (bf16_t)qn1;
    v_buf[oidx]     = v0;
    v_buf[oidx + 1] = v1;
}

// ---------------- flash attention: one wave owns 16 q-rows ----------------
__global__ __launch_bounds__(256) void k_attn(const bf16_t* __restrict__ Q,
                                              const bf16_t* __restrict__ Kb,
                                              const bf16_t* __restrict__ Vb,
                                              int Lk,
                                              bf16_t* __restrict__ out,
                                              int out_sl, int out_sh,
                                              const bf16_t* __restrict__ addsrc,
                                              const float* __restrict__ ip_scale_p) {
    __shared__ bf16_t k_sh[64 * 136];
    __shared__ bf16_t vT_sh[128 * 72];
    __shared__ bf16_t p_sh[4][16 * 72];
    const int tid = threadIdx.x, wave = tid >> 6, lane = tid & 63;
    const int qd = lane >> 4, tr = lane & 15;
    const int h = blockIdx.y;
    const int q0 = blockIdx.x * 64 + wave * 16;
    const bf16_t* Qh = Q + ((size_t)h * LQ + q0 + tr) * HD;
    bf16x8 qf[4];
#pragma unroll
    for (int ks = 0; ks < 4; ks++) qf[ks] = *(const bf16x8*)(Qh + ks * 32 + qd * 8);
    float m_r[4], l_r[4];
    f32x4 accO[8];
    const f32x4 z = {0.f, 0.f, 0.f, 0.f};
#pragma unroll
    for (int r = 0; r < 4; r++) { m_r[r] = -1e30f; l_r[r] = 0.f; }
#pragma unroll
    for (int dt = 0; dt < 8; dt++) accO[dt] = z;
    const float sc = 0.08838834764831843f;  // 1/sqrt(128)

    for (int kt = 0; kt < Lk; kt += 64) {
        __syncthreads();
        {   // stage K tile (64 x 128) row-major
            int r = tid >> 2, ds = (tid & 3) * 32;
            const bf16_t* src = Kb + ((size_t)h * Lk + kt + r) * HD + ds;
#pragma unroll
            for (int u = 0; u < 4; u++)
                *(bf16x8*)(k_sh + r * 136 + ds + u * 8) = *(const bf16x8*)(src + u * 8);
        }
        {   // stage V^T tile (128 x 64)
            int kv = (tid >> 3) * 2, dv = (tid & 7) * 16;
            const bf16_t* s0 = Vb + ((size_t)h * Lk + kt + kv) * HD + dv;
            bf16x8 va0 = *(const bf16x8*)(s0);
            bf16x8 va1 = *(const bf16x8*)(s0 + 8);
            bf16x8 vb0 = *(const bf16x8*)(s0 + HD);
            bf16x8 vb1 = *(const bf16x8*)(s0 + HD + 8);
#pragma unroll
            for (int j = 0; j < 8; j++) {
                bf16x2 pr = {va0[j], vb0[j]};
                *(bf16x2*)(vT_sh + (dv + j) * 72 + kv) = pr;
            }
#pragma unroll
            for (int j = 0; j < 8; j++) {
                bf16x2 pr = {va1[j], vb1[j]};
                *(bf16x2*)(vT_sh + (dv + 8 + j) * 72 + kv) = pr;
            }
        }
        __syncthreads();
        // S = Q K^T  (4 n-tiles of 16 keys)
        f32x4 s4[4];
#pragma unroll
        for (int nt = 0; nt < 4; nt++) {
            f32x4 a = z;
#pragma unroll
            for (int ks = 0; ks < 4; ks++) {
                bf16x8 kf = *(const bf16x8*)(k_sh + (nt * 16 + tr) * 136 + ks * 32 + qd * 8);
                a = mfma16(qf[ks], kf, a);
            }
            s4[nt] = a;
        }
        // online softmax per q-row (rows qd*4+r owned by the 16-lane col group)
#pragma unroll
        for (int r = 0; r < 4; r++) {
            float x0 = s4[0][r] * sc, x1 = s4[1][r] * sc;
            float x2 = s4[2][r] * sc, x3 = s4[3][r] * sc;
            float mx = fmaxf(fmaxf(x0, x1), fmaxf(x2, x3));
            mx = fmaxf(mx, __shfl_xor(mx, 1));
            mx = fmaxf(mx, __shfl_xor(mx, 2));
            mx = fmaxf(mx, __shfl_xor(mx, 4));
            mx = fmaxf(mx, __shfl_xor(mx, 8));
            float mnew  = fmaxf(m_r[r], mx);
            float alpha = __expf(m_r[r] - mnew);
            m_r[r] = mnew;
            float p0 = __expf(x0 - mnew), p1 = __expf(x1 - mnew);
            float p2 = __expf(x2 - mnew), p3 = __expf(x3 - mnew);
            float rs = p0 + p1 + p2 + p3;
            rs += __shfl_xor(rs, 1);
            rs += __shfl_xor(rs, 2);
            rs += __shfl_xor(rs, 4);
            rs += __shfl_xor(rs, 8);
            l_r[r] = l_r[r] * alpha + rs;
            int prow = qd * 4 + r;
            bf16_t* pp = &p_sh[wave][prow * 72 + tr];
            pp[0]  = (bf16_t)p0;
            pp[16] = (bf16_t)p1;
            pp[32] = (bf16_t)p2;
            pp[48] = (bf16_t)p3;
#pragma unroll
            for (int dt = 0; dt < 8; dt++) accO[dt][r] *= alpha;
        }
        // O += P V   (P from LDS in A-layout, V^T for b128 B-frags)
#pragma unroll
        for (int ks2 = 0; ks2 < 2; ks2++) {
            bf16x8 pf = *(const bf16x8*)(&p_sh[wave][tr * 72 + ks2 * 32 + qd * 8]);
#pragma unroll
            for (int dt = 0; dt < 8; dt++) {
                bf16x8 vf = *(const bf16x8*)(vT_sh + (dt * 16 + tr) * 72 + ks2 * 32 + qd * 8);
                accO[dt] = mfma16(pf, vf, accO[dt]);
            }
        }
    }
    // epilogue
    float scl = (ip_scale_p != nullptr) ? *ip_scale_p : 0.f;
#pragma unroll
    for (int dt = 0; dt < 8; dt++) {
        int d = dt * 16 + tr;
#pragma unroll
        for (int r = 0; r < 4; r++) {
            int row = q0 + qd * 4 + r;
            float o = accO[dt][r] / l_r[r];
            if (addsrc) o += scl * (float)addsrc[((size_t)h * LQ + row) * HD + d];
            out[(size_t)row * out_sl + (size_t)h * out_sh + d] = (bf16_t)o;
        }
    }
}

// ---------------- launch ----------------
extern "C" void kernel_launch(void* const* d_in, const int* in_sizes, int n_in,
                              void* d_out, int out_size, void* d_ws, size_t ws_size,
                              hipStream_t stream) {
    const float* x       = (const float*)d_in[0];
    const float* vec     = (const float*)d_in[1];
    const float* pe      = (const float*)d_in[2];
    const float* ip      = (const float*)d_in[3];
    const float* ipscale = (const float*)d_in[4];
    const float* mod_w   = (const float*)d_in[5];
    const float* mod_b   = (const float*)d_in[6];
    const float* w1      = (const float*)d_in[7];
    const float* b1      = (const float*)d_in[8];
    const float* w2      = (const float*)d_in[9];
    const float* b2      = (const float*)d_in[10];
    const float* qs      = (const float*)d_in[11];
    const float* ksc     = (const float*)d_in[12];
    const float* wk      = (const float*)d_in[13];
    const float* wv      = (const float*)d_in[14];
    float* out = (float*)d_out;

    char* ws = (char*)d_ws;
    const size_t OFF_MOD   = 0;                          // 9216 f32
    const size_t OFF_XMOD  = 36864;                      // 2048*3072 bf16
    const size_t OFF_HQ    = OFF_XMOD + 12582912ULL;     // 2048*9216 bf16
    const size_t OFF_FUSED = OFF_HQ   + 37748736ULL;     // 2048*15360 bf16
    const size_t OFF_QR    = OFF_FUSED + 62914560ULL;    // (H,L,D) bf16
    const size_t OFF_KR    = OFF_QR + 12582912ULL;
    const size_t OFF_V     = OFF_KR + 12582912ULL;
    const size_t OFF_QP    = OFF_V  + 12582912ULL;
    const size_t OFF_IPO   = OFF_QP + 12582912ULL;
    const size_t OFF_IPB   = OFF_IPO + 12582912ULL;      // 64*4096 bf16
    const size_t OFF_IPK   = OFF_IPB + 524288ULL;        // (H,64,128) bf16
    const size_t OFF_IPV   = OFF_IPK + 393216ULL;

    float*  mod     = (float*)(ws + OFF_MOD);
    bf16_t* x_mod   = (bf16_t*)(ws + OFF_XMOD);
    bf16_t* hq      = (bf16_t*)(ws + OFF_HQ);
    bf16_t* fused   = (bf16_t*)(ws + OFF_FUSED);
    bf16_t* q_rope  = (bf16_t*)(ws + OFF_QR);
    bf16_t* k_rope  = (bf16_t*)(ws + OFF_KR);
    bf16_t* v_buf   = (bf16_t*)(ws + OFF_V);
    bf16_t* q_plain = (bf16_t*)(ws + OFF_QP);
    bf16_t* ip_out  = (bf16_t*)(ws + OFF_IPO);
    bf16_t* ipb     = (bf16_t*)(ws + OFF_IPB);
    bf16_t* ipk     = (bf16_t*)(ws + OFF_IPK);
    bf16_t* ipv     = (bf16_t*)(ws + OFF_IPV);

    k_convert<<<256, 256, 0, stream>>>(ip, ipb, 65536);
    k_mod_gemv<<<2304, 256, 0, stream>>>(vec, mod_w, mod_b, mod);
    k_ln_mod<<<2048, 256, 0, stream>>>(x, mod, x_mod);
    k_gemm_l1<<<dim3(16, 168), 256, 0, stream>>>(x_mod, w1, b1, hq, fused);
    k_qkv_post<<<12288, 256, 0, stream>>>(hq, pe, qs, ksc, q_rope, k_rope, q_plain, v_buf);
    k_gemm_ip<<<dim3(48, 2), 256, 0, stream>>>(ipb, wk, wv, ipk, ipv);
    // ip attention: q_plain vs 64 image keys -> ip_out (H,L,D)
    k_attn<<<dim3(32, 24), 256, 0, stream>>>(q_plain, ipk, ipv, 64,
                                             ip_out, HD, LQ * HD, nullptr, nullptr);
    // self attention (+ ip_scale*ip_out) -> fused[:, 0:3072]
    k_attn<<<dim3(32, 24), 256, 0, stream>>>(q_rope, k_rope, v_buf, LQ,
                                             fused, N2, HD, ip_out, ipscale);
    k_gemm_l2<<<dim3(16, 24), 256, 0, stream>>>(fused, w2, b2, x, mod + 6144, out);
}

// Round 2
// 1623.932 us; speedup vs baseline: 1.1680x; 1.1680x over previous
//
#include <hip/hip_runtime.h>
#include <hip/hip_bf16.h>
#include <math.h>

typedef __bf16 bf16_t;
typedef __bf16 bf16x8 __attribute__((ext_vector_type(8)));
typedef __bf16 bf16x4 __attribute__((ext_vector_type(4)));
typedef __bf16 bf16x2 __attribute__((ext_vector_type(2)));
typedef float  f32x4  __attribute__((ext_vector_type(4)));

#define HIDN 3072
#define LQ   2048
#define NH   24
#define HD   128
#define N1   21504   // 3*HID + MLP
#define N2   15360   // HID + MLP
#define KIP  4096

__device__ __forceinline__ f32x4 mfma16(bf16x8 a, bf16x8 b, f32x4 c) {
    return __builtin_amdgcn_mfma_f32_16x16x32_bf16(a, b, c, 0, 0, 0);
}

__device__ __forceinline__ float wave_sum64(float v) {
#pragma unroll
    for (int off = 1; off < 64; off <<= 1) v += __shfl_xor(v, off);
    return v;
}

// async 16B global->LDS; dst must be the wave-uniform base (HW adds lane*16B)
__device__ __forceinline__ void gld16(bf16_t* dst_lds, const bf16_t* src) {
    __builtin_amdgcn_global_load_lds(
        (const __attribute__((address_space(1))) void*)src,
        (__attribute__((address_space(3))) void*)dst_lds, 16, 0, 0);
}

// ---------------- fp32 -> bf16 bulk convert (grid = ceil(n4/256)) ----------------
__global__ void k_convert(const float* __restrict__ in, bf16_t* __restrict__ out, int n4) {
    int i = blockIdx.x * blockDim.x + threadIdx.x;
    if (i < n4) {
        float4 f = ((const float4*)in)[i];
        bf16x4 h = {(bf16_t)f.x, (bf16_t)f.y, (bf16_t)f.z, (bf16_t)f.w};
        *(bf16x4*)(out + (size_t)i * 4) = h;
    }
}

// ---------------- mod = silu(vec) @ W^T + b  (9216 rows) ----------------
__global__ __launch_bounds__(256) void k_mod_gemv(const float* __restrict__ vec,
                                                  const float* __restrict__ W,
                                                  const float* __restrict__ b,
                                                  float* __restrict__ mod) {
    int row  = blockIdx.x * 4 + (threadIdx.x >> 6);
    int lane = threadIdx.x & 63;
    const float4* W4 = (const float4*)(W + (size_t)row * HIDN);
    const float4* V4 = (const float4*)vec;
    float s = 0.f;
#pragma unroll
    for (int i = 0; i < 12; i++) {
        float4 w = W4[lane + i * 64];
        float4 v = V4[lane + i * 64];
        s += w.x * (v.x / (1.f + __expf(-v.x)));
        s += w.y * (v.y / (1.f + __expf(-v.y)));
        s += w.z * (v.z / (1.f + __expf(-v.z)));
        s += w.w * (v.w / (1.f + __expf(-v.w)));
    }
    s = wave_sum64(s);
    if (lane == 0) mod[row] = s + b[row];
}

// ---------------- x_mod = (1+scale)*LN(x) + shift, bf16 out ----------------
__global__ __launch_bounds__(256) void k_ln_mod(const float* __restrict__ x,
                                                const float* __restrict__ mod,
                                                bf16_t* __restrict__ x_mod) {
    int row = blockIdx.x, tid = threadIdx.x;
    const float* xr = x + (size_t)row * HIDN;
    float v[12];
    float s = 0.f, ss = 0.f;
#pragma unroll
    for (int p = 0; p < 12; p++) {
        v[p] = xr[tid + p * 256];
        s += v[p]; ss += v[p] * v[p];
    }
    s = wave_sum64(s); ss = wave_sum64(ss);
    __shared__ float red[8];
    int wave = tid >> 6, lane = tid & 63;
    if (lane == 0) { red[wave] = s; red[4 + wave] = ss; }
    __syncthreads();
    float S  = red[0] + red[1] + red[2] + red[3];
    float SS = red[4] + red[5] + red[6] + red[7];
    float mean = S * (1.f / HIDN);
    float var  = SS * (1.f / HIDN) - mean * mean;
    float rstd = rsqrtf(var + 1e-6f);
#pragma unroll
    for (int p = 0; p < 12; p++) {
        int j = tid + p * 256;
        float xm = (v[p] - mean) * rstd;
        float y  = (1.f + mod[HIDN + j]) * xm + mod[j];
        x_mod[(size_t)row * HIDN + j] = (bf16_t)y;
    }
}

// ================= bf16-weight GEMM core (m97 structure) =================
// A (MxK bf16, K-contig), W (NxK bf16, K-contig). 128x128 tile, BK=32.
// LDS tiles unpadded 128x32, staged with global_load_lds dwordx4.
__device__ __forceinline__ void gemm_core_b(const bf16_t* __restrict__ A,
                                            const bf16_t* __restrict__ W,
                                            int K, int m0, int n0,
                                            bf16_t* a_sh, bf16_t* b_sh,
                                            f32x4 acc[4][4]) {
    const int tid = threadIdx.x;
    const int wave = tid >> 6, lane = tid & 63;
    const int qd = lane >> 4, tr = lane & 15;
    const int wm = (wave >> 1) * 64, wn = (wave & 1) * 64;
    const int r = tid >> 2, s = tid & 3;
    const bf16_t* Ab  = A + (size_t)(m0 + r) * K + s * 8;
    const bf16_t* Ab2 = Ab + (size_t)64 * K;
    const bf16_t* Wb  = W + (size_t)(n0 + r) * K + s * 8;
    const bf16_t* Wb2 = Wb + (size_t)64 * K;
    bf16_t* a_dst = a_sh + wave * 512;   // wave-uniform LDS base
    bf16_t* b_dst = b_sh + wave * 512;
    for (int k0 = 0; k0 < K; k0 += 32) {
        __syncthreads();
        gld16(a_dst,        Ab  + k0);
        gld16(a_dst + 2048, Ab2 + k0);
        gld16(b_dst,        Wb  + k0);
        gld16(b_dst + 2048, Wb2 + k0);
        __syncthreads();
        bf16x8 af[4], bfr[4];
#pragma unroll
        for (int t = 0; t < 4; t++)
            af[t] = *(const bf16x8*)(a_sh + (wm + t * 16 + tr) * 32 + qd * 8);
#pragma unroll
        for (int t = 0; t < 4; t++)
            bfr[t] = *(const bf16x8*)(b_sh + (wn + t * 16 + tr) * 32 + qd * 8);
#pragma unroll
        for (int mt = 0; mt < 4; mt++)
#pragma unroll
            for (int nt = 0; nt < 4; nt++)
                acc[mt][nt] = mfma16(af[mt], bfr[nt], acc[mt][nt]);
    }
}

__global__ __launch_bounds__(256) void k_gemm_l1_b(const bf16_t* __restrict__ A,
                                                   const bf16_t* __restrict__ W,
                                                   const float* __restrict__ bias,
                                                   bf16_t* __restrict__ hq,
                                                   bf16_t* __restrict__ fused) {
    __shared__ bf16_t a_sh[128 * 32];
    __shared__ bf16_t b_sh[128 * 32];
    f32x4 acc[4][4];
    const f32x4 z = {0.f, 0.f, 0.f, 0.f};
#pragma unroll
    for (int mt = 0; mt < 4; mt++)
#pragma unroll
        for (int nt = 0; nt < 4; nt++) acc[mt][nt] = z;
    int m0 = blockIdx.x * 128, n0 = blockIdx.y * 128;
    gemm_core_b(A, W, HIDN, m0, n0, a_sh, b_sh, acc);
    const int tid = threadIdx.x, wave = tid >> 6, lane = tid & 63;
    const int qd = lane >> 4, tr = lane & 15;
    const int wm = (wave >> 1) * 64, wn = (wave & 1) * 64;
#pragma unroll
    for (int mt = 0; mt < 4; mt++)
#pragma unroll
        for (int nt = 0; nt < 4; nt++) {
            int col = n0 + wn + nt * 16 + tr;
            float bb = bias[col];
            f32x4 v = acc[mt][nt];
#pragma unroll
            for (int r = 0; r < 4; r++) {
                int row = m0 + wm + mt * 16 + qd * 4 + r;
                float val = v[r] + bb;
                if (col < 9216) {
                    hq[(size_t)row * 9216 + col] = (bf16_t)val;
                } else {
                    float g = 0.5f * val *
                        (1.f + tanhf(0.7978845608028654f * (val + 0.044715f * val * val * val)));
                    fused[(size_t)row * N2 + HIDN + (col - 9216)] = (bf16_t)g;
                }
            }
        }
}

__global__ __launch_bounds__(256) void k_gemm_l2_b(const bf16_t* __restrict__ A,
                                                   const bf16_t* __restrict__ W,
                                                   const float* __restrict__ bias,
                                                   const float* __restrict__ x,
                                                   const float* __restrict__ gate,
                                                   float* __restrict__ out) {
    __shared__ bf16_t a_sh[128 * 32];
    __shared__ bf16_t b_sh[128 * 32];
    f32x4 acc[4][4];
    const f32x4 z = {0.f, 0.f, 0.f, 0.f};
#pragma unroll
    for (int mt = 0; mt < 4; mt++)
#pragma unroll
        for (int nt = 0; nt < 4; nt++) acc[mt][nt] = z;
    int m0 = blockIdx.x * 128, n0 = blockIdx.y * 128;
    gemm_core_b(A, W, N2, m0, n0, a_sh, b_sh, acc);
    const int tid = threadIdx.x, wave = tid >> 6, lane = tid & 63;
    const int qd = lane >> 4, tr = lane & 15;
    const int wm = (wave >> 1) * 64, wn = (wave & 1) * 64;
#pragma unroll
    for (int mt = 0; mt < 4; mt++)
#pragma unroll
        for (int nt = 0; nt < 4; nt++) {
            int col = n0 + wn + nt * 16 + tr;
            float bb = bias[col];
            float g  = gate[col];
#pragma unroll
            for (int r = 0; r < 4; r++) {
                int row = m0 + wm + mt * 16 + qd * 4 + r;
                size_t idx = (size_t)row * HIDN + col;
                out[idx] = x[idx] + g * (acc[mt][nt][r] + bb);
            }
        }
}

// ip_k/ip_v with bf16 weights: (64x4096)@(3072x4096)^T -> (H,64,128)
__global__ __launch_bounds__(256) void k_gemm_ip_b(const bf16_t* __restrict__ A,
                                                   const bf16_t* __restrict__ Wk,
                                                   const bf16_t* __restrict__ Wv,
                                                   bf16_t* __restrict__ outk,
                                                   bf16_t* __restrict__ outv) {
    __shared__ bf16_t a_sh[64 * 32];
    __shared__ bf16_t b_sh[64 * 32];
    const bf16_t* W = (blockIdx.y == 0) ? Wk : Wv;
    bf16_t* out    = (blockIdx.y == 0) ? outk : outv;
    int n0 = blockIdx.x * 64;
    const int tid = threadIdx.x, wave = tid >> 6, lane = tid & 63;
    const int qd = lane >> 4, tr = lane & 15;
    const int r = tid >> 2, s = tid & 3;
    const bf16_t* Ab = A + (size_t)r * KIP + s * 8;
    const bf16_t* Wb = W + (size_t)(n0 + r) * KIP + s * 8;
    bf16_t* a_dst = a_sh + wave * 512;
    bf16_t* b_dst = b_sh + wave * 512;
    f32x4 acc[4];
    const f32x4 z = {0.f, 0.f, 0.f, 0.f};
#pragma unroll
    for (int mt = 0; mt < 4; mt++) acc[mt] = z;
    for (int k0 = 0; k0 < KIP; k0 += 32) {
        __syncthreads();
        gld16(a_dst, Ab + k0);
        gld16(b_dst, Wb + k0);
        __syncthreads();
        bf16x8 bfrag = *(const bf16x8*)(b_sh + (wave * 16 + tr) * 32 + qd * 8);
#pragma unroll
        for (int mt = 0; mt < 4; mt++) {
            bf16x8 afrag = *(const bf16x8*)(a_sh + (mt * 16 + tr) * 32 + qd * 8);
            acc[mt] = mfma16(afrag, bfrag, acc[mt]);
        }
    }
    int col = n0 + wave * 16 + tr;
    int h = col >> 7, d = col & 127;
#pragma unroll
    for (int mt = 0; mt < 4; mt++)
#pragma unroll
        for (int r2 = 0; r2 < 4; r2++) {
            int row = mt * 16 + qd * 4 + r2;
            out[((size_t)h * 64 + row) * HD + d] = (bf16_t)acc[mt][r2];
        }
}

// ================= fp32-weight fallback GEMM (round-0 path) =================
__device__ __forceinline__ void gemm_core_f32(const bf16_t* __restrict__ A,
                                              const float* __restrict__ W,
                                              int K, int m0, int n0,
                                              bf16_t* a_sh, bf16_t* b_sh,
                                              f32x4 acc[4][4]) {
    const int tid = threadIdx.x;
    const int wave = tid >> 6, lane = tid & 63;
    const int qd = lane >> 4, tr = lane & 15;
    const int wm = (wave >> 1) * 64, wn = (wave & 1) * 64;
    for (int k0 = 0; k0 < K; k0 += 32) {
        __syncthreads();
#pragma unroll
        for (int i = 0; i < 2; i++) {
            int flat = tid + i * 256;
            int r = flat >> 2, s = flat & 3;
            *(bf16x8*)(a_sh + r * 40 + s * 8) =
                *(const bf16x8*)(A + (size_t)(m0 + r) * K + k0 + s * 8);
        }
#pragma unroll
        for (int i = 0; i < 4; i++) {
            int flat = tid + i * 256;
            int r = flat >> 3, s = flat & 7;
            float4 f = *(const float4*)(W + (size_t)(n0 + r) * K + k0 + s * 4);
            bf16x4 h = {(bf16_t)f.x, (bf16_t)f.y, (bf16_t)f.z, (bf16_t)f.w};
            *(bf16x4*)(b_sh + r * 40 + s * 4) = h;
        }
        __syncthreads();
        bf16x8 af[4], bfr[4];
#pragma unroll
        for (int t = 0; t < 4; t++)
            af[t] = *(const bf16x8*)(a_sh + (wm + t * 16 + tr) * 40 + qd * 8);
#pragma unroll
        for (int t = 0; t < 4; t++)
            bfr[t] = *(const bf16x8*)(b_sh + (wn + t * 16 + tr) * 40 + qd * 8);
#pragma unroll
        for (int mt = 0; mt < 4; mt++)
#pragma unroll
            for (int nt = 0; nt < 4; nt++)
                acc[mt][nt] = mfma16(af[mt], bfr[nt], acc[mt][nt]);
    }
}

__global__ __launch_bounds__(256) void k_gemm_l1_f(const bf16_t* __restrict__ A,
                                                   const float* __restrict__ W,
                                                   const float* __restrict__ bias,
                                                   bf16_t* __restrict__ hq,
                                                   bf16_t* __restrict__ fused) {
    __shared__ bf16_t a_sh[128 * 40];
    __shared__ bf16_t b_sh[128 * 40];
    f32x4 acc[4][4];
    const f32x4 z = {0.f, 0.f, 0.f, 0.f};
#pragma unroll
    for (int mt = 0; mt < 4; mt++)
#pragma unroll
        for (int nt = 0; nt < 4; nt++) acc[mt][nt] = z;
    int m0 = blockIdx.x * 128, n0 = blockIdx.y * 128;
    gemm_core_f32(A, W, HIDN, m0, n0, a_sh, b_sh, acc);
    const int tid = threadIdx.x, wave = tid >> 6, lane = tid & 63;
    const int qd = lane >> 4, tr = lane & 15;
    const int wm = (wave >> 1) * 64, wn = (wave & 1) * 64;
#pragma unroll
    for (int mt = 0; mt < 4; mt++)
#pragma unroll
        for (int nt = 0; nt < 4; nt++) {
            int col = n0 + wn + nt * 16 + tr;
            float bb = bias[col];
            f32x4 v = acc[mt][nt];
#pragma unroll
            for (int r = 0; r < 4; r++) {
                int row = m0 + wm + mt * 16 + qd * 4 + r;
                float val = v[r] + bb;
                if (col < 9216) {
                    hq[(size_t)row * 9216 + col] = (bf16_t)val;
                } else {
                    float g = 0.5f * val *
                        (1.f + tanhf(0.7978845608028654f * (val + 0.044715f * val * val * val)));
                    fused[(size_t)row * N2 + HIDN + (col - 9216)] = (bf16_t)g;
                }
            }
        }
}

__global__ __launch_bounds__(256) void k_gemm_l2_f(const bf16_t* __restrict__ A,
                                                   const float* __restrict__ W,
                                                   const float* __restrict__ bias,
                                                   const float* __restrict__ x,
                                                   const float* __restrict__ gate,
                                                   float* __restrict__ out) {
    __shared__ bf16_t a_sh[128 * 40];
    __shared__ bf16_t b_sh[128 * 40];
    f32x4 acc[4][4];
    const f32x4 z = {0.f, 0.f, 0.f, 0.f};
#pragma unroll
    for (int mt = 0; mt < 4; mt++)
#pragma unroll
        for (int nt = 0; nt < 4; nt++) acc[mt][nt] = z;
    int m0 = blockIdx.x * 128, n0 = blockIdx.y * 128;
    gemm_core_f32(A, W, N2, m0, n0, a_sh, b_sh, acc);
    const int tid = threadIdx.x, wave = tid >> 6, lane = tid & 63;
    const int qd = lane >> 4, tr = lane & 15;
    const int wm = (wave >> 1) * 64, wn = (wave & 1) * 64;
#pragma unroll
    for (int mt = 0; mt < 4; mt++)
#pragma unroll
        for (int nt = 0; nt < 4; nt++) {
            int col = n0 + wn + nt * 16 + tr;
            float bb = bias[col];
            float g  = gate[col];
#pragma unroll
            for (int r = 0; r < 4; r++) {
                int row = m0 + wm + mt * 16 + qd * 4 + r;
                size_t idx = (size_t)row * HIDN + col;
                out[idx] = x[idx] + g * (acc[mt][nt][r] + bb);
            }
        }
}

__global__ __launch_bounds__(256) void k_gemm_ip_f(const bf16_t* __restrict__ A,
                                                   const float* __restrict__ Wk,
                                                   const float* __restrict__ Wv,
                                                   bf16_t* __restrict__ outk,
                                                   bf16_t* __restrict__ outv) {
    __shared__ bf16_t a_sh[64 * 40];
    __shared__ bf16_t b_sh[64 * 40];
    const float* W = (blockIdx.y == 0) ? Wk : Wv;
    bf16_t* out    = (blockIdx.y == 0) ? outk : outv;
    int n0 = blockIdx.x * 64;
    const int tid = threadIdx.x, wave = tid >> 6, lane = tid & 63;
    const int qd = lane >> 4, tr = lane & 15;
    f32x4 acc[4];
    const f32x4 z = {0.f, 0.f, 0.f, 0.f};
#pragma unroll
    for (int mt = 0; mt < 4; mt++) acc[mt] = z;
    for (int k0 = 0; k0 < KIP; k0 += 32) {
        __syncthreads();
        {
            int r = tid >> 2, s = tid & 3;
            *(bf16x8*)(a_sh + r * 40 + s * 8) =
                *(const bf16x8*)(A + (size_t)r * KIP + k0 + s * 8);
        }
#pragma unroll
        for (int i = 0; i < 2; i++) {
            int flat = tid + i * 256;
            int r = flat >> 3, s = flat & 7;
            float4 f = *(const float4*)(W + (size_t)(n0 + r) * KIP + k0 + s * 4);
            bf16x4 h = {(bf16_t)f.x, (bf16_t)f.y, (bf16_t)f.z, (bf16_t)f.w};
            *(bf16x4*)(b_sh + r * 40 + s * 4) = h;
        }
        __syncthreads();
        bf16x8 bfrag = *(const bf16x8*)(b_sh + (wave * 16 + tr) * 40 + qd * 8);
#pragma unroll
        for (int mt = 0; mt < 4; mt++) {
            bf16x8 afrag = *(const bf16x8*)(a_sh + (mt * 16 + tr) * 40 + qd * 8);
            acc[mt] = mfma16(afrag, bfrag, acc[mt]);
        }
    }
    int col = n0 + wave * 16 + tr;
    int h = col >> 7, d = col & 127;
#pragma unroll
    for (int mt = 0; mt < 4; mt++)
#pragma unroll
        for (int r = 0; r < 4; r++) {
            int row = mt * 16 + qd * 4 + r;
            out[((size_t)h * 64 + row) * HD + d] = (bf16_t)acc[mt][r];
        }
}

// ---------------- qkv post: rmsnorm + rope, repack to (H,L,D) bf16 ----------------
__global__ __launch_bounds__(256) void k_qkv_post(const bf16_t* __restrict__ hq,
                                                  const float* __restrict__ pe,
                                                  const float* __restrict__ qs,
                                                  const float* __restrict__ ksc,
                                                  bf16_t* __restrict__ q_rope,
                                                  bf16_t* __restrict__ k_rope,
                                                  bf16_t* __restrict__ q_plain,
                                                  bf16_t* __restrict__ v_buf) {
    int wid  = blockIdx.x * 4 + (threadIdx.x >> 6);
    int lane = threadIdx.x & 63;
    int l = wid / NH, h = wid % NH;
    const bf16_t* base = hq + (size_t)l * 9216 + h * HD;
    int d0 = lane * 2;
    float q0 = (float)base[d0],        q1 = (float)base[d0 + 1];
    float k0 = (float)base[3072 + d0], k1 = (float)base[3072 + d0 + 1];
    bf16_t v0 = base[6144 + d0],       v1 = base[6144 + d0 + 1];
    float ssq = wave_sum64(q0 * q0 + q1 * q1);
    float ssk = wave_sum64(k0 * k0 + k1 * k1);
    float rq = rsqrtf(ssq * (1.f / HD) + 1e-6f);
    float rk = rsqrtf(ssk * (1.f / HD) + 1e-6f);
    float qn0 = q0 * rq * qs[d0], qn1 = q1 * rq * qs[d0 + 1];
    float kn0 = k0 * rk * ksc[d0], kn1 = k1 * rk * ksc[d0 + 1];
    const float* pp = pe + ((size_t)l * 64 + lane) * 4;
    float c00 = pp[0], c01 = pp[1], c10 = pp[2], c11 = pp[3];
    size_t oidx = ((size_t)h * LQ + l) * HD + d0;
    q_rope[oidx]     = (bf16_t)(c00 * qn0 + c01 * qn1);
    q_rope[oidx + 1] = (bf16_t)(c10 * qn0 + c11 * qn1);
    k_rope[oidx]     = (bf16_t)(c00 * kn0 + c01 * kn1);
    k_rope[oidx + 1] = (bf16_t)(c10 * kn0 + c11 * kn1);
    q_plain[oidx]     = (bf16_t)qn0;
    q_plain[oidx + 1] = (bf16_t)qn1;
    v_buf[oidx]     = v0;
    v_buf[oidx + 1] = v1;
}

// ---------------- flash attention: one wave owns 16 q-rows ----------------
__global__ __launch_bounds__(256) void k_attn(const bf16_t* __restrict__ Q,
                                              const bf16_t* __restrict__ Kb,
                                              const bf16_t* __restrict__ Vb,
                                              int Lk,
                                              bf16_t* __restrict__ out,
                                              int out_sl, int out_sh,
                                              const bf16_t* __restrict__ addsrc,
                                              const float* __restrict__ ip_scale_p) {
    __shared__ bf16_t k_sh[64 * 136];
    __shared__ bf16_t vT_sh[128 * 72];
    __shared__ bf16_t p_sh[4][16 * 72];
    const int tid = threadIdx.x, wave = tid >> 6, lane = tid & 63;
    const int qd = lane >> 4, tr = lane & 15;
    const int h = blockIdx.y;
    const int q0 = blockIdx.x * 64 + wave * 16;
    const bf16_t* Qh = Q + ((size_t)h * LQ + q0 + tr) * HD;
    bf16x8 qf[4];
#pragma unroll
    for (int ks = 0; ks < 4; ks++) qf[ks] = *(const bf16x8*)(Qh + ks * 32 + qd * 8);
    float m_r[4], l_r[4];
    f32x4 accO[8];
    const f32x4 z = {0.f, 0.f, 0.f, 0.f};
#pragma unroll
    for (int r = 0; r < 4; r++) { m_r[r] = -1e30f; l_r[r] = 0.f; }
#pragma unroll
    for (int dt = 0; dt < 8; dt++) accO[dt] = z;
    const float sc = 0.08838834764831843f;  // 1/sqrt(128)

    for (int kt = 0; kt < Lk; kt += 64) {
        __syncthreads();
        {   // stage K tile (64 x 128) row-major
            int r = tid >> 2, ds = (tid & 3) * 32;
            const bf16_t* src = Kb + ((size_t)h * Lk + kt + r) * HD + ds;
#pragma unroll
            for (int u = 0; u < 4; u++)
                *(bf16x8*)(k_sh + r * 136 + ds + u * 8) = *(const bf16x8*)(src + u * 8);
        }
        {   // stage V^T tile (128 x 64)
            int kv = (tid >> 3) * 2, dv = (tid & 7) * 16;
            const bf16_t* s0 = Vb + ((size_t)h * Lk + kt + kv) * HD + dv;
            bf16x8 va0 = *(const bf16x8*)(s0);
            bf16x8 va1 = *(const bf16x8*)(s0 + 8);
            bf16x8 vb0 = *(const bf16x8*)(s0 + HD);
            bf16x8 vb1 = *(const bf16x8*)(s0 + HD + 8);
#pragma unroll
            for (int j = 0; j < 8; j++) {
                bf16x2 pr = {va0[j], vb0[j]};
                *(bf16x2*)(vT_sh + (dv + j) * 72 + kv) = pr;
            }
#pragma unroll
            for (int j = 0; j < 8; j++) {
                bf16x2 pr = {va1[j], vb1[j]};
                *(bf16x2*)(vT_sh + (dv + 8 + j) * 72 + kv) = pr;
            }
        }
        __syncthreads();
        // S = Q K^T  (4 n-tiles of 16 keys)
        f32x4 s4[4];
#pragma unroll
        for (int nt = 0; nt < 4; nt++) {
            f32x4 a = z;
#pragma unroll
            for (int ks = 0; ks < 4; ks++) {
                bf16x8 kf = *(const bf16x8*)(k_sh + (nt * 16 + tr) * 136 + ks * 32 + qd * 8);
                a = mfma16(qf[ks], kf, a);
            }
            s4[nt] = a;
        }
        // online softmax per q-row
#pragma unroll
        for (int r = 0; r < 4; r++) {
            float x0 = s4[0][r] * sc, x1 = s4[1][r] * sc;
            float x2 = s4[2][r] * sc, x3 = s4[3][r] * sc;
            float mx = fmaxf(fmaxf(x0, x1), fmaxf(x2, x3));
            mx = fmaxf(mx, __shfl_xor(mx, 1));
            mx = fmaxf(mx, __shfl_xor(mx, 2));
            mx = fmaxf(mx, __shfl_xor(mx, 4));
            mx = fmaxf(mx, __shfl_xor(mx, 8));
            float mnew  = fmaxf(m_r[r], mx);
            float alpha = __expf(m_r[r] - mnew);
            m_r[r] = mnew;
            float p0 = __expf(x0 - mnew), p1 = __expf(x1 - mnew);
            float p2 = __expf(x2 - mnew), p3 = __expf(x3 - mnew);
            float rs = p0 + p1 + p2 + p3;
            rs += __shfl_xor(rs, 1);
            rs += __shfl_xor(rs, 2);
            rs += __shfl_xor(rs, 4);
            rs += __shfl_xor(rs, 8);
            l_r[r] = l_r[r] * alpha + rs;
            int prow = qd * 4 + r;
            bf16_t* pp = &p_sh[wave][prow * 72 + tr];
            pp[0]  = (bf16_t)p0;
            pp[16] = (bf16_t)p1;
            pp[32] = (bf16_t)p2;
            pp[48] = (bf16_t)p3;
#pragma unroll
            for (int dt = 0; dt < 8; dt++) accO[dt][r] *= alpha;
        }
        // O += P V
#pragma unroll
        for (int ks2 = 0; ks2 < 2; ks2++) {
            bf16x8 pf = *(const bf16x8*)(&p_sh[wave][tr * 72 + ks2 * 32 + qd * 8]);
#pragma unroll
            for (int dt = 0; dt < 8; dt++) {
                bf16x8 vf = *(const bf16x8*)(vT_sh + (dt * 16 + tr) * 72 + ks2 * 32 + qd * 8);
                accO[dt] = mfma16(pf, vf, accO[dt]);
            }
        }
    }
    // epilogue
    float scl = (ip_scale_p != nullptr) ? *ip_scale_p : 0.f;
#pragma unroll
    for (int dt = 0; dt < 8; dt++) {
        int d = dt * 16 + tr;
#pragma unroll
        for (int r = 0; r < 4; r++) {
            int row = q0 + qd * 4 + r;
            float o = accO[dt][r] / l_r[r];
            if (addsrc) o += scl * (float)addsrc[((size_t)h * LQ + row) * HD + d];
            out[(size_t)row * out_sl + (size_t)h * out_sh + d] = (bf16_t)o;
        }
    }
}

// ---------------- launch ----------------
extern "C" void kernel_launch(void* const* d_in, const int* in_sizes, int n_in,
                              void* d_out, int out_size, void* d_ws, size_t ws_size,
                              hipStream_t stream) {
    const float* x       = (const float*)d_in[0];
    const float* vec     = (const float*)d_in[1];
    const float* pe      = (const float*)d_in[2];
    const float* ip      = (const float*)d_in[3];
    const float* ipscale = (const float*)d_in[4];
    const float* mod_w   = (const float*)d_in[5];
    const float* mod_b   = (const float*)d_in[6];
    const float* w1      = (const float*)d_in[7];
    const float* b1      = (const float*)d_in[8];
    const float* w2      = (const float*)d_in[9];
    const float* b2      = (const float*)d_in[10];
    const float* qs      = (const float*)d_in[11];
    const float* ksc     = (const float*)d_in[12];
    const float* wk      = (const float*)d_in[13];
    const float* wv      = (const float*)d_in[14];
    float* out = (float*)d_out;

    char* ws = (char*)d_ws;
    const size_t OFF_MOD   = 0;                          // 9216 f32
    const size_t OFF_XMOD  = 36864;                      // 2048*3072 bf16
    const size_t OFF_HQ    = OFF_XMOD + 12582912ULL;     // 2048*9216 bf16
    const size_t OFF_FUSED = OFF_HQ   + 37748736ULL;     // 2048*15360 bf16
    const size_t OFF_QR    = OFF_FUSED + 62914560ULL;    // (H,L,D) bf16
    const size_t OFF_KR    = OFF_QR + 12582912ULL;
    const size_t OFF_V     = OFF_KR + 12582912ULL;
    const size_t OFF_QP    = OFF_V  + 12582912ULL;
    const size_t OFF_IPO   = OFF_QP + 12582912ULL;
    const size_t OFF_IPB   = OFF_IPO + 12582912ULL;      // 64*4096 bf16
    const size_t OFF_IPK   = OFF_IPB + 524288ULL;        // (H,64,128) bf16
    const size_t OFF_IPV   = OFF_IPK + 393216ULL;
    const size_t OFF_WB    = OFF_IPV + 393216ULL;        // 132 MB reuse region
    const size_t WB_BYTES  = 132120576ULL;               // w1 bf16
    const size_t WS_NEED   = OFF_WB + WB_BYTES;

    float*  mod     = (float*)(ws + OFF_MOD);
    bf16_t* x_mod   = (bf16_t*)(ws + OFF_XMOD);
    bf16_t* hq      = (bf16_t*)(ws + OFF_HQ);
    bf16_t* fused   = (bf16_t*)(ws + OFF_FUSED);
    bf16_t* q_rope  = (bf16_t*)(ws + OFF_QR);
    bf16_t* k_rope  = (bf16_t*)(ws + OFF_KR);
    bf16_t* v_buf   = (bf16_t*)(ws + OFF_V);
    bf16_t* q_plain = (bf16_t*)(ws + OFF_QP);
    bf16_t* ip_out  = (bf16_t*)(ws + OFF_IPO);
    bf16_t* ipb     = (bf16_t*)(ws + OFF_IPB);
    bf16_t* ipk     = (bf16_t*)(ws + OFF_IPK);
    bf16_t* ipv     = (bf16_t*)(ws + OFF_IPV);
    bf16_t* wbuf    = (bf16_t*)(ws + OFF_WB);

    const bool big_ws = (ws_size >= WS_NEED);

    k_convert<<<256, 256, 0, stream>>>(ip, ipb, 65536);
    k_mod_gemv<<<2304, 256, 0, stream>>>(vec, mod_w, mod_b, mod);
    k_ln_mod<<<2048, 256, 0, stream>>>(x, mod, x_mod);

    if (big_ws) {
        // linear1 with pre-converted bf16 weights
        k_convert<<<64512, 256, 0, stream>>>(w1, wbuf, 16515072);          // 66.06M elems
        k_gemm_l1_b<<<dim3(16, 168), 256, 0, stream>>>(x_mod, wbuf, b1, hq, fused);
    } else {
        k_gemm_l1_f<<<dim3(16, 168), 256, 0, stream>>>(x_mod, w1, b1, hq, fused);
    }

    k_qkv_post<<<12288, 256, 0, stream>>>(hq, pe, qs, ksc, q_rope, k_rope, q_plain, v_buf);

    if (big_ws) {
        bf16_t* wkb = wbuf;
        bf16_t* wvb = wbuf + 12582912;   // 3072*4096 elems each
        k_convert<<<12288, 256, 0, stream>>>(wk, wkb, 3145728);
        k_convert<<<12288, 256, 0, stream>>>(wv, wvb, 3145728);
        k_gemm_ip_b<<<dim3(48, 2), 256, 0, stream>>>(ipb, wkb, wvb, ipk, ipv);
    } else {
        k_gemm_ip_f<<<dim3(48, 2), 256, 0, stream>>>(ipb, wk, wv, ipk, ipv);
    }

    // ip attention: q_plain vs 64 image keys -> ip_out (H,L,D)
    k_attn<<<dim3(32, 24), 256, 0, stream>>>(q_plain, ipk, ipv, 64,
                                             ip_out, HD, LQ * HD, nullptr, nullptr);
    // self attention (+ ip_scale*ip_out) -> fused[:, 0:3072]
    k_attn<<<dim3(32, 24), 256, 0, stream>>>(q_rope, k_rope, v_buf, LQ,
                                             fused, N2, HD, ip_out, ipscale);

    if (big_ws) {
        k_convert<<<46080, 256, 0, stream>>>(w2, wbuf, 11796480);          // 47.19M elems
        k_gemm_l2_b<<<dim3(16, 24), 256, 0, stream>>>(fused, wbuf, b2, x, mod + 6144, out);
    } else {
        k_gemm_l2_f<<<dim3(16, 24), 256, 0, stream>>>(fused, w2, b2, x, mod + 6144, out);
    }
}